// Round 2
// baseline (9257.909 us; speedup 1.0000x reference)
//
#include <hip/hip_runtime.h>
#include <hip/hip_bf16.h>

#define S_LEN 4096
#define HID   512          // per-direction hidden
#define E_DIM 512
#define G4    2048         // 4*H

__device__ __forceinline__ float fsig(float x) {
  return __fdividef(1.f, 1.f + __expf(-x));
}
__device__ __forceinline__ float ftanh_(float x) {
  return 1.f - __fdividef(2.f, __expf(2.f * x) + 1.f);
}
__device__ __forceinline__ unsigned int f2b(float f) {          // fp32 -> bf16 bits (RNE)
  unsigned int x = __float_as_uint(f);
  return (x + 0x7FFFu + ((x >> 16) & 1u)) >> 16;
}
__device__ __forceinline__ float b2f(unsigned int b) {          // bf16 bits -> fp32
  return __uint_as_float(b << 16);
}

// ---------------------------------------------------------------------------
// Phase 1: xp_dir[t][j] = sum_e emb[id(t)][e] * wih_dir[j][e] + b_dir[j]
// 128x128 tile, 8x8 micro-tile, TK=16, LDS pad 132 (16B-aligned rows).
// ---------------------------------------------------------------------------
__global__ __launch_bounds__(256) void proj_gemm(
    const int* __restrict__ ids, const float* __restrict__ emb,
    const float* __restrict__ wih_f, const float* __restrict__ wih_b,
    const float* __restrict__ b_f, const float* __restrict__ b_b,
    float* __restrict__ xp_f, float* __restrict__ xp_b)
{
  const int dir = blockIdx.z;
  const float* __restrict__ wih  = dir ? wih_b : wih_f;
  const float* __restrict__ bias = dir ? b_b : b_f;
  float* __restrict__ out = dir ? xp_b : xp_f;
  const int i0 = blockIdx.y * 128;
  const int j0 = blockIdx.x * 128;
  __shared__ __align__(16) float As[16 * 132];
  __shared__ __align__(16) float Bs[16 * 132];
  const int tid = threadIdx.x;
  const int ti = tid >> 4, tj = tid & 15;

  // staging roles: two (row, k4) assignments per thread
  const int r0 = tid >> 2,        k40 = tid & 3;
  const int r1 = (tid + 256) >> 2, k41 = (tid + 256) & 3;
  const int id0 = ids[dir ? (S_LEN - 1 - (i0 + r0)) : (i0 + r0)];
  const int id1 = ids[dir ? (S_LEN - 1 - (i0 + r1)) : (i0 + r1)];
  const float* a0p = emb + (size_t)id0 * E_DIM + k40 * 4;
  const float* a1p = emb + (size_t)id1 * E_DIM + k41 * 4;
  const float* b0p = wih + (size_t)(j0 + r0) * E_DIM + k40 * 4;
  const float* b1p = wih + (size_t)(j0 + r1) * E_DIM + k41 * 4;

  float acc[8][8];
  #pragma unroll
  for (int x = 0; x < 8; ++x)
    #pragma unroll
    for (int y = 0; y < 8; ++y) acc[x][y] = 0.f;

  for (int k0 = 0; k0 < E_DIM; k0 += 16) {
    float4 va0 = *(const float4*)(a0p + k0);
    float4 va1 = *(const float4*)(a1p + k0);
    float4 vb0 = *(const float4*)(b0p + k0);
    float4 vb1 = *(const float4*)(b1p + k0);
    As[(k40*4+0)*132 + r0] = va0.x; As[(k40*4+1)*132 + r0] = va0.y;
    As[(k40*4+2)*132 + r0] = va0.z; As[(k40*4+3)*132 + r0] = va0.w;
    As[(k41*4+0)*132 + r1] = va1.x; As[(k41*4+1)*132 + r1] = va1.y;
    As[(k41*4+2)*132 + r1] = va1.z; As[(k41*4+3)*132 + r1] = va1.w;
    Bs[(k40*4+0)*132 + r0] = vb0.x; Bs[(k40*4+1)*132 + r0] = vb0.y;
    Bs[(k40*4+2)*132 + r0] = vb0.z; Bs[(k40*4+3)*132 + r0] = vb0.w;
    Bs[(k41*4+0)*132 + r1] = vb1.x; Bs[(k41*4+1)*132 + r1] = vb1.y;
    Bs[(k41*4+2)*132 + r1] = vb1.z; Bs[(k41*4+3)*132 + r1] = vb1.w;
    __syncthreads();
    const float4* As4 = (const float4*)As;   // row stride 33 float4
    const float4* Bs4 = (const float4*)Bs;
    #pragma unroll
    for (int k = 0; k < 16; ++k) {
      float4 al = As4[k*33 + ti];
      float4 ah = As4[k*33 + 16 + ti];
      float4 bl = Bs4[k*33 + tj];
      float4 bh = Bs4[k*33 + 16 + tj];
      float a[8] = {al.x, al.y, al.z, al.w, ah.x, ah.y, ah.z, ah.w};
      float b[8] = {bl.x, bl.y, bl.z, bl.w, bh.x, bh.y, bh.z, bh.w};
      #pragma unroll
      for (int x = 0; x < 8; ++x)
        #pragma unroll
        for (int y = 0; y < 8; ++y) acc[x][y] = fmaf(a[x], b[y], acc[x][y]);
    }
    __syncthreads();
  }
  float4 blo = *(const float4*)(bias + j0 + tj * 4);
  float4 bhi = *(const float4*)(bias + j0 + 64 + tj * 4);
  #pragma unroll
  for (int x = 0; x < 8; ++x) {
    int gi = i0 + ((x < 4) ? (ti * 4 + x) : (64 + ti * 4 + (x - 4)));
    float* orow = out + (size_t)gi * G4 + j0;
    float4 o0 = make_float4(acc[x][0] + blo.x, acc[x][1] + blo.y,
                            acc[x][2] + blo.z, acc[x][3] + blo.w);
    float4 o1 = make_float4(acc[x][4] + bhi.x, acc[x][5] + bhi.y,
                            acc[x][6] + bhi.z, acc[x][7] + bhi.w);
    *(float4*)(orow + tj * 4) = o0;
    *(float4*)(orow + 64 + tj * 4) = o1;
  }
}

// ---------------------------------------------------------------------------
// Phase 2: both LSTM recurrences. 32 WGs x 512 thr. WG (dir,g) owns hidden
// units [g*32, g*32+32) and gate rows {gate*512 + unit}. Weights in VGPRs
// (128 fp32/thread). Cross-WG h broadcast: u32 word = (tag16<<16)|bf16(h),
// device-scope relaxed atomics, slot depth 4.
// ---------------------------------------------------------------------------
__global__ __launch_bounds__(512, 2) void lstm_rec(
    const float* __restrict__ xp_f, const float* __restrict__ xp_b,
    const float* __restrict__ whh_f, const float* __restrict__ whh_b,
    float* __restrict__ hs, unsigned int* __restrict__ hslot)
{
  const int wg  = blockIdx.x;
  const int dir = wg >> 4, g = wg & 15;
  const float* __restrict__ xp  = dir ? xp_b  : xp_f;
  const float* __restrict__ whh = dir ? whh_b : whh_f;
  unsigned int* slot = hslot + dir * (4 * HID);
  const int tid  = threadIdx.x;
  const int lr   = tid >> 2;        // local gate row 0..127
  const int p    = tid & 3;         // column quarter
  const int gate = lr >> 5;         // 0:i 1:f 2:g 3:o
  const int uoff = lr & 31;
  const int U0   = g * 32;
  const int grow = gate * 512 + U0 + uoff;

  float w[128];
  {
    const float4* wp = (const float4*)(whh + (size_t)grow * HID + p * 128);
    #pragma unroll
    for (int u = 0; u < 32; ++u) {
      float4 v = wp[u];
      w[4*u] = v.x; w[4*u+1] = v.y; w[4*u+2] = v.z; w[4*u+3] = v.w;
    }
  }
  __shared__ __align__(16) float h_lds[528];   // 4 segments of 132 (128 + pad)
  __shared__ float gates_lds[128];
  for (int q = tid; q < 528; q += 512) h_lds[q] = 0.f;   // h_0 = 0
  __syncthreads();

  float c = 0.f;
  float xpv = (p == 0) ? xp[grow] : 0.f;                 // xp[0][grow]
  const int myslot_pos = (tid >> 7) * 132 + (tid & 127); // where polled h lands

  for (int t = 0; t < S_LEN; ++t) {
    float a0 = 0.f, a1 = 0.f, a2 = 0.f, a3 = 0.f;
    const float4* hq = (const float4*)(h_lds + p * 132);
    #pragma unroll
    for (int u = 0; u < 32; ++u) {
      float4 hv = hq[u];
      a0 = fmaf(w[4*u],   hv.x, a0);
      a1 = fmaf(w[4*u+1], hv.y, a1);
      a2 = fmaf(w[4*u+2], hv.z, a2);
      a3 = fmaf(w[4*u+3], hv.w, a3);
    }
    float acc = (a0 + a1) + (a2 + a3);
    acc += __shfl_xor(acc, 1);
    acc += __shfl_xor(acc, 2);
    if (p == 0) gates_lds[lr] = acc + xpv;
    __syncthreads();
    if (p == 0 && t + 1 < S_LEN) xpv = xp[(size_t)(t + 1) * G4 + grow];
    const unsigned int tagn = (unsigned int)(t + 1);
    if (tid < 32) {
      float gi_ = gates_lds[tid];
      float gf_ = gates_lds[32 + tid];
      float gg_ = gates_lds[64 + tid];
      float go_ = gates_lds[96 + tid];
      float i_ = fsig(gi_), f_ = fsig(gf_), g2 = ftanh_(gg_), o_ = fsig(go_);
      c = f_ * c + i_ * g2;
      float h = o_ * ftanh_(c);
      const int trow = dir ? (S_LEN - 1 - t) : t;
      hs[(size_t)trow * 1024 + dir * HID + U0 + tid] = h;
      __hip_atomic_store(&slot[(tagn & 3) * HID + U0 + tid],
                         (tagn << 16) | f2b(h),
                         __ATOMIC_RELAXED, __HIP_MEMORY_SCOPE_AGENT);
    }
    if (t + 1 < S_LEN) {
      const unsigned int want = tagn << 16;
      unsigned int* pw = &slot[(tagn & 3) * HID + tid];
      unsigned int v; int guard = 0;
      for (;;) {
        v = __hip_atomic_load(pw, __ATOMIC_RELAXED, __HIP_MEMORY_SCOPE_AGENT);
        if ((v & 0xFFFF0000u) == want) break;
        if (++guard > (1 << 24)) break;     // bail-out: wrong answer, not hang
        __builtin_amdgcn_s_sleep(1);
      }
      h_lds[myslot_pos] = b2f(v & 0xFFFFu);
    }
    __syncthreads();
  }
}

// ---------------------------------------------------------------------------
// Phase 3: em[t][tag] = lstm_out[t] . lin_w[tag] + lin_b[tag]
// 256 WGs x 512 thr; 16 t-rows staged in LDS per WG.
// ---------------------------------------------------------------------------
__global__ __launch_bounds__(512) void emis_kernel(
    const float* __restrict__ hs, const float* __restrict__ lin_w,
    const float* __restrict__ lin_b, float* __restrict__ em)
{
  __shared__ float4 rows[4096];   // 16 rows x 1024 fp32 = 64 KiB
  const int t0 = blockIdx.x * 16;
  const int tid = threadIdx.x;
  const float4* hs4 = (const float4*)(hs + (size_t)t0 * 1024);
  #pragma unroll
  for (int it = 0; it < 8; ++it) rows[it * 512 + tid] = hs4[it * 512 + tid];
  __syncthreads();
  const int r = tid >> 5, tag = tid & 31;
  const float4* w4 = (const float4*)(lin_w + (size_t)tag * 1024);
  float acc = 0.f;
  #pragma unroll 4
  for (int k = 0; k < 256; ++k) {
    float4 h = rows[r * 256 + k];
    float4 w = w4[k];
    acc += h.x * w.x + h.y * w.y + h.z * w.z + h.w * w.w;
  }
  em[(size_t)(t0 + r) * 32 + tag] = acc + lin_b[tag];
}

// ---------------------------------------------------------------------------
// Phase 4: CRF NLL. One wave: gold score (lane-strided) + sequential
// forward algorithm (lane = tag j, halves split the i-sum 16/16).
// ---------------------------------------------------------------------------
__global__ __launch_bounds__(64) void crf_kernel(
    const float* __restrict__ em, const int* __restrict__ tgt,
    const float* __restrict__ start_t, const float* __restrict__ end_t,
    const float* __restrict__ trans, float* __restrict__ out)
{
  const int lane = threadIdx.x;
  // gold path score
  float se = 0.f;
  for (int t = lane; t < S_LEN; t += 64) {
    se += em[(size_t)t * 32 + tgt[t]];
    if (t + 1 < S_LEN) se += trans[tgt[t] * 32 + tgt[t + 1]];
  }
  #pragma unroll
  for (int m = 1; m < 64; m <<= 1) se += __shfl_xor(se, m);
  const float score = se + start_t[tgt[0]] + end_t[tgt[S_LEN - 1]];

  // forward algorithm
  __shared__ __align__(16) float al[32];
  const int j = lane & 31, half = lane >> 5, i0 = half * 16;
  float tr[16];
  #pragma unroll
  for (int u = 0; u < 16; ++u) tr[u] = trans[(i0 + u) * 32 + j];
  if (lane < 32) al[j] = start_t[j] + em[j];
  __syncthreads();
  float ep = em[32 + j];   // em[1][j] prefetched
  for (int t = 1; t < S_LEN; ++t) {
    float epn = (t + 1 < S_LEN) ? em[(size_t)(t + 1) * 32 + j] : 0.f;
    float v[16];
    const float4* a4 = (const float4*)al;
    #pragma unroll
    for (int q = 0; q < 4; ++q) {
      float4 av = a4[half * 4 + q];
      v[4*q]   = av.x + tr[4*q];
      v[4*q+1] = av.y + tr[4*q+1];
      v[4*q+2] = av.z + tr[4*q+2];
      v[4*q+3] = av.w + tr[4*q+3];
    }
    float m = v[0];
    #pragma unroll
    for (int u = 1; u < 16; ++u) m = fmaxf(m, v[u]);
    m = fmaxf(m, __shfl_xor(m, 32));
    float s = 0.f;
    #pragma unroll
    for (int u = 0; u < 16; ++u) s += __expf(v[u] - m);
    s += __shfl_xor(s, 32);
    float an = m + __logf(s) + ep;
    __syncthreads();
    if (half == 0) al[j] = an;
    __syncthreads();
    ep = epn;
  }
  float x = (lane < 32) ? al[j] + end_t[j] : -1e30f;
  float mm = x;
  #pragma unroll
  for (int m2 = 1; m2 < 64; m2 <<= 1) mm = fmaxf(mm, __shfl_xor(mm, m2));
  float ss = (lane < 32) ? __expf(x - mm) : 0.f;
  #pragma unroll
  for (int m2 = 1; m2 < 64; m2 <<= 1) ss += __shfl_xor(ss, m2);
  if (lane == 0) out[0] = (mm + __logf(ss)) - score;
}

// ---------------------------------------------------------------------------
extern "C" void kernel_launch(void* const* d_in, const int* in_sizes, int n_in,
                              void* d_out, int out_size, void* d_ws, size_t ws_size,
                              hipStream_t stream) {
  const int*   ids   = (const int*)d_in[0];
  const int*   tgt   = (const int*)d_in[1];
  const float* emb   = (const float*)d_in[2];
  const float* wih_f = (const float*)d_in[3];
  const float* whh_f = (const float*)d_in[4];
  const float* b_f   = (const float*)d_in[5];
  const float* wih_b = (const float*)d_in[6];
  const float* whh_b = (const float*)d_in[7];
  const float* b_b   = (const float*)d_in[8];
  const float* lin_w = (const float*)d_in[9];
  const float* lin_b = (const float*)d_in[10];
  const float* st    = (const float*)d_in[11];
  const float* et    = (const float*)d_in[12];
  const float* trans = (const float*)d_in[13];

  float* xp_f = (float*)d_ws;                                   // 4096*2048
  float* xp_b = xp_f + (size_t)S_LEN * G4;                      // 4096*2048
  float* hs   = xp_b + (size_t)S_LEN * G4;                      // 4096*1024
  float* em   = hs   + (size_t)S_LEN * 1024;                    // 4096*32
  unsigned int* slot = (unsigned int*)(em + (size_t)S_LEN * 32);// 2 dirs * 4 * 512

  proj_gemm<<<dim3(16, 32, 2), dim3(256), 0, stream>>>(
      ids, emb, wih_f, wih_b, b_f, b_b, xp_f, xp_b);
  lstm_rec<<<dim3(32), dim3(512), 0, stream>>>(
      xp_f, xp_b, whh_f, whh_b, hs, slot);
  emis_kernel<<<dim3(256), dim3(512), 0, stream>>>(hs, lin_w, lin_b, em);
  crf_kernel<<<dim3(1), dim3(64), 0, stream>>>(em, tgt, st, et, trans,
                                               (float*)d_out);
}

// Round 3
// 8078.318 us; speedup vs baseline: 1.1460x; 1.1460x over previous
//
#include <hip/hip_runtime.h>
#include <hip/hip_bf16.h>

#define S_LEN 4096
#define HID   512          // per-direction hidden
#define E_DIM 512
#define G4    2048         // 4*H

__device__ __forceinline__ unsigned int f2b(float f) {          // fp32 -> bf16 bits (RNE)
  unsigned int x = __float_as_uint(f);
  return (x + 0x7FFFu + ((x >> 16) & 1u)) >> 16;
}
__device__ __forceinline__ float b2f(unsigned int b) {          // bf16 bits -> fp32
  return __uint_as_float(b << 16);
}

// ---------------------------------------------------------------------------
// Phase 1: xp_dir[t][j] = sum_e emb[id(t)][e] * wih_dir[j][e] + b_dir[j]
// 128x128 tile, 8x8 micro-tile, TK=16, LDS pad 132 (16B-aligned rows).
// ---------------------------------------------------------------------------
__global__ __launch_bounds__(256) void proj_gemm(
    const int* __restrict__ ids, const float* __restrict__ emb,
    const float* __restrict__ wih_f, const float* __restrict__ wih_b,
    const float* __restrict__ b_f, const float* __restrict__ b_b,
    float* __restrict__ xp_f, float* __restrict__ xp_b)
{
  const int dir = blockIdx.z;
  const float* __restrict__ wih  = dir ? wih_b : wih_f;
  const float* __restrict__ bias = dir ? b_b : b_f;
  float* __restrict__ out = dir ? xp_b : xp_f;
  const int i0 = blockIdx.y * 128;
  const int j0 = blockIdx.x * 128;
  __shared__ __align__(16) float As[16 * 132];
  __shared__ __align__(16) float Bs[16 * 132];
  const int tid = threadIdx.x;
  const int ti = tid >> 4, tj = tid & 15;

  const int r0 = tid >> 2,        k40 = tid & 3;
  const int r1 = (tid + 256) >> 2, k41 = (tid + 256) & 3;
  const int id0 = ids[dir ? (S_LEN - 1 - (i0 + r0)) : (i0 + r0)];
  const int id1 = ids[dir ? (S_LEN - 1 - (i0 + r1)) : (i0 + r1)];
  const float* a0p = emb + (size_t)id0 * E_DIM + k40 * 4;
  const float* a1p = emb + (size_t)id1 * E_DIM + k41 * 4;
  const float* b0p = wih + (size_t)(j0 + r0) * E_DIM + k40 * 4;
  const float* b1p = wih + (size_t)(j0 + r1) * E_DIM + k41 * 4;

  float acc[8][8];
  #pragma unroll
  for (int x = 0; x < 8; ++x)
    #pragma unroll
    for (int y = 0; y < 8; ++y) acc[x][y] = 0.f;

  for (int k0 = 0; k0 < E_DIM; k0 += 16) {
    float4 va0 = *(const float4*)(a0p + k0);
    float4 va1 = *(const float4*)(a1p + k0);
    float4 vb0 = *(const float4*)(b0p + k0);
    float4 vb1 = *(const float4*)(b1p + k0);
    As[(k40*4+0)*132 + r0] = va0.x; As[(k40*4+1)*132 + r0] = va0.y;
    As[(k40*4+2)*132 + r0] = va0.z; As[(k40*4+3)*132 + r0] = va0.w;
    As[(k41*4+0)*132 + r1] = va1.x; As[(k41*4+1)*132 + r1] = va1.y;
    As[(k41*4+2)*132 + r1] = va1.z; As[(k41*4+3)*132 + r1] = va1.w;
    Bs[(k40*4+0)*132 + r0] = vb0.x; Bs[(k40*4+1)*132 + r0] = vb0.y;
    Bs[(k40*4+2)*132 + r0] = vb0.z; Bs[(k40*4+3)*132 + r0] = vb0.w;
    Bs[(k41*4+0)*132 + r1] = vb1.x; Bs[(k41*4+1)*132 + r1] = vb1.y;
    Bs[(k41*4+2)*132 + r1] = vb1.z; Bs[(k41*4+3)*132 + r1] = vb1.w;
    __syncthreads();
    const float4* As4 = (const float4*)As;   // row stride 33 float4
    const float4* Bs4 = (const float4*)Bs;
    #pragma unroll
    for (int k = 0; k < 16; ++k) {
      float4 al = As4[k*33 + ti];
      float4 ah = As4[k*33 + 16 + ti];
      float4 bl = Bs4[k*33 + tj];
      float4 bh = Bs4[k*33 + 16 + tj];
      float a[8] = {al.x, al.y, al.z, al.w, ah.x, ah.y, ah.z, ah.w};
      float b[8] = {bl.x, bl.y, bl.z, bl.w, bh.x, bh.y, bh.z, bh.w};
      #pragma unroll
      for (int x = 0; x < 8; ++x)
        #pragma unroll
        for (int y = 0; y < 8; ++y) acc[x][y] = fmaf(a[x], b[y], acc[x][y]);
    }
    __syncthreads();
  }
  float4 blo = *(const float4*)(bias + j0 + tj * 4);
  float4 bhi = *(const float4*)(bias + j0 + 64 + tj * 4);
  #pragma unroll
  for (int x = 0; x < 8; ++x) {
    int gi = i0 + ((x < 4) ? (ti * 4 + x) : (64 + ti * 4 + (x - 4)));
    float* orow = out + (size_t)gi * G4 + j0;
    float4 o0 = make_float4(acc[x][0] + blo.x, acc[x][1] + blo.y,
                            acc[x][2] + blo.z, acc[x][3] + blo.w);
    float4 o1 = make_float4(acc[x][4] + bhi.x, acc[x][5] + bhi.y,
                            acc[x][6] + bhi.z, acc[x][7] + bhi.w);
    *(float4*)(orow + tj * 4) = o0;
    *(float4*)(orow + 64 + tj * 4) = o1;
  }
}

// ---------------------------------------------------------------------------
// Phase 2: both LSTM recurrences. 32 WGs x 512 thr. WG (dir,g) owns 32 units.
// Lane map: tid = u_l*16 + gate*4 + p. All 4 gates of a unit in one wave ->
// shfl-only reduction, one barrier/step, double-buffered h LDS.
// Cross-WG h broadcast: u32 word = (tag16<<16)|bf16(h), agent-scope relaxed.
// ---------------------------------------------------------------------------
__global__ __launch_bounds__(512, 2) void lstm_rec(
    const float* __restrict__ xp_f, const float* __restrict__ xp_b,
    const float* __restrict__ whh_f, const float* __restrict__ whh_b,
    float* __restrict__ hs, unsigned int* __restrict__ hslot)
{
  const int wg  = blockIdx.x;
  const int dir = wg >> 4, g = wg & 15;
  const float* __restrict__ xp  = dir ? xp_b  : xp_f;
  const float* __restrict__ whh = dir ? whh_b : whh_f;
  unsigned int* slot = hslot + dir * (4 * HID);
  const int tid  = threadIdx.x;
  const int lane = tid & 63;
  const int u_l  = tid >> 4;         // local unit 0..31
  const int gate = (tid >> 2) & 3;   // 0:i 1:f 2:g 3:o
  const int p    = tid & 3;          // column quarter
  const int U0   = g * 32;
  const int grow = gate * 512 + U0 + u_l;
  const bool isg = (gate == 2);
  const bool master = ((tid & 15) == 0);

  float w[128];
  {
    const float4* wp = (const float4*)(whh + (size_t)grow * HID + p * 128);
    #pragma unroll
    for (int u = 0; u < 32; ++u) {
      float4 v = wp[u];
      w[4*u] = v.x; w[4*u+1] = v.y; w[4*u+2] = v.z; w[4*u+3] = v.w;
    }
  }
  __shared__ __align__(16) float h_lds[2][544];   // 4 segments of 136
  const int pollpos = (tid >> 7) * 136 + (tid & 127);   // slot for unit `tid`
  const int ownunit = U0 + u_l;
  const int ownpos  = (ownunit >> 7) * 136 + (ownunit & 127);
  h_lds[0][pollpos] = 0.f;           // h_0 = 0
  __syncthreads();

  float c = 0.f;
  float xpv = xp[grow];              // xp[0][grow]
  int buf = 0;
  const unsigned int rel = (unsigned int)(tid - U0);   // <32u -> own unit

  for (int t = 0; t < S_LEN; ++t) {
    float a0 = 0.f, a1 = 0.f, a2 = 0.f, a3 = 0.f;
    const float4* hq = (const float4*)(&h_lds[buf][p * 136]);
    #pragma unroll
    for (int u = 0; u < 32; ++u) {
      float4 hv = hq[u];
      a0 = fmaf(w[4*u],   hv.x, a0);
      a1 = fmaf(w[4*u+1], hv.y, a1);
      a2 = fmaf(w[4*u+2], hv.z, a2);
      a3 = fmaf(w[4*u+3], hv.w, a3);
    }
    float acc = (a0 + a1) + (a2 + a3);
    acc += __shfl_xor(acc, 1);
    acc += __shfl_xor(acc, 2);
    float v = acc + xpv;
    if (t + 1 < S_LEN) xpv = xp[(size_t)(t + 1) * G4 + grow];  // prefetch

    // branch-free activation: sigmoid for i,f,o; tanh for g
    float e = __expf(isg ? (v + v) : -v);
    float r = __fdividef(1.f, 1.f + e);
    float act = isg ? (1.f - 2.f * r) : r;
    float a4  = __shfl(act, (lane + 4)  & 63);
    float a8  = __shfl(act, (lane + 8)  & 63);
    float a12 = __shfl(act, (lane + 12) & 63);

    const unsigned int tagn = (unsigned int)(t + 1);
    if (master) {
      float i_ = act, f_ = a4, g_ = a8, o_ = a12;
      c = f_ * c + i_ * g_;
      float e2 = __expf(c + c);
      float th = 1.f - 2.f * __fdividef(1.f, 1.f + e2);
      float h = o_ * th;
      unsigned int hb = f2b(h);
      __hip_atomic_store(&slot[(tagn & 3) * HID + ownunit],
                         (tagn << 16) | hb,
                         __ATOMIC_RELAXED, __HIP_MEMORY_SCOPE_AGENT);
      h_lds[buf ^ 1][ownpos] = b2f(hb);     // own unit direct (consistent bf16)
      const int trow = dir ? (S_LEN - 1 - t) : t;
      hs[(size_t)trow * 1024 + dir * HID + ownunit] = h;
    }
    if (t + 1 < S_LEN) {
      if (rel >= 32u) {                       // remote unit: poll MALL word
        const unsigned int want = tagn;
        unsigned int* pw = &slot[(tagn & 3) * HID + tid];
        unsigned int vv; int it = 0;
        for (;;) {
          vv = __hip_atomic_load(pw, __ATOMIC_RELAXED, __HIP_MEMORY_SCOPE_AGENT);
          if ((vv >> 16) == want) break;
          if (++it > 64) __builtin_amdgcn_s_sleep(1);
          if (it > (1 << 22)) break;          // bail-out: wrong, not hung
        }
        h_lds[buf ^ 1][pollpos] = b2f(vv & 0xFFFFu);
      }
      __syncthreads();
    }
    buf ^= 1;
  }
}

// ---------------------------------------------------------------------------
// Phase 3: em[t][tag] = lstm_out[t] . lin_w[tag] + lin_b[tag]
// ---------------------------------------------------------------------------
__global__ __launch_bounds__(512) void emis_kernel(
    const float* __restrict__ hs, const float* __restrict__ lin_w,
    const float* __restrict__ lin_b, float* __restrict__ em)
{
  __shared__ float4 rows[4096];   // 16 rows x 1024 fp32 = 64 KiB
  const int t0 = blockIdx.x * 16;
  const int tid = threadIdx.x;
  const float4* hs4 = (const float4*)(hs + (size_t)t0 * 1024);
  #pragma unroll
  for (int it = 0; it < 8; ++it) rows[it * 512 + tid] = hs4[it * 512 + tid];
  __syncthreads();
  const int r = tid >> 5, tag = tid & 31;
  const float4* w4 = (const float4*)(lin_w + (size_t)tag * 1024);
  float acc = 0.f;
  #pragma unroll 4
  for (int k = 0; k < 256; ++k) {
    float4 h = rows[r * 256 + k];
    float4 w = w4[k];
    acc += h.x * w.x + h.y * w.y + h.z * w.z + h.w * w.w;
  }
  em[(size_t)(t0 + r) * 32 + tag] = acc + lin_b[tag];
}

// ---------------------------------------------------------------------------
// Phase 4a: CRF chunk products. Chunk c folds M_t (t in [max(1,16c),16c+16))
// where M_t[i,j] = trans[i,j] + em[t][j], in the logsumexp semiring.
// Output transposed: Pt[c][j*32+i] = P_c[i][j].
// ---------------------------------------------------------------------------
__global__ __launch_bounds__(1024) void crf_pass1(
    const float* __restrict__ em, const float* __restrict__ trans,
    float* __restrict__ Pt)
{
  __shared__ float tr[32 * 33];
  __shared__ float bufA[32 * 33], bufB[32 * 33];
  const int tid = threadIdx.x;
  const int i = tid >> 5, j = tid & 31;
  tr[i * 33 + j] = trans[i * 32 + j];
  const int c = blockIdx.x;
  const int t0 = (c == 0) ? 1 : c * 16;
  const int t1 = c * 16 + 16;
  bufA[i * 33 + j] = trans[i * 32 + j] + em[(size_t)t0 * 32 + j];
  __syncthreads();

  float* cur = bufA;
  float* nxt = bufB;
  for (int t = t0 + 1; t < t1; ++t) {
    float m = -1e30f;
    #pragma unroll
    for (int k = 0; k < 32; ++k)
      m = fmaxf(m, cur[i * 33 + k] + tr[k * 33 + j]);
    float s = 0.f;
    #pragma unroll
    for (int k = 0; k < 32; ++k)
      s += __expf(cur[i * 33 + k] + tr[k * 33 + j] - m);
    float nv = m + __logf(s) + em[(size_t)t * 32 + j];
    nxt[i * 33 + j] = nv;
    __syncthreads();
    float* tmp = cur; cur = nxt; nxt = tmp;
  }
  // store transposed: Pt[c*1024 + j*32 + i] = cur[i][j]
  Pt[(size_t)c * 1024 + tid] = cur[(tid & 31) * 33 + (tid >> 5)];
}

// ---------------------------------------------------------------------------
// Phase 4b: scan 256 chunk matrices (wave 0) + gold score (wave 1); NLL out.
// ---------------------------------------------------------------------------
__global__ __launch_bounds__(128) void crf_pass2(
    const float* __restrict__ em, const float* __restrict__ Pt,
    const int* __restrict__ tgt, const float* __restrict__ st,
    const float* __restrict__ et, const float* __restrict__ trans,
    float* __restrict__ out)
{
  __shared__ float als[32];
  __shared__ float gold[2];
  const int tid = threadIdx.x;
  const int lane = tid & 63;
  const int wv = tid >> 6;

  if (wv == 1) {
    float se = 0.f;
    for (int t = lane; t < S_LEN; t += 64) {
      int tg = tgt[t];
      se += em[(size_t)t * 32 + tg];
      if (t + 1 < S_LEN) se += trans[tg * 32 + tgt[t + 1]];
    }
    #pragma unroll
    for (int m = 1; m < 64; m <<= 1) se += __shfl_xor(se, m);
    if (lane == 0) gold[0] = se + st[tgt[0]] + et[tgt[S_LEN - 1]];
  } else {
    const int jj = lane & 31;
    float a = st[jj] + em[jj];
    float4 P0, P1, P2, P3, P4, P5, P6, P7;
    {
      const float* pb = Pt + jj * 32;
      P0 = *(const float4*)(pb +  0); P1 = *(const float4*)(pb +  4);
      P2 = *(const float4*)(pb +  8); P3 = *(const float4*)(pb + 12);
      P4 = *(const float4*)(pb + 16); P5 = *(const float4*)(pb + 20);
      P6 = *(const float4*)(pb + 24); P7 = *(const float4*)(pb + 28);
    }
    for (int cc = 0; cc < 256; ++cc) {
      float4 N0, N1, N2, N3, N4, N5, N6, N7;
      if (cc < 255) {
        const float* pb = Pt + (size_t)(cc + 1) * 1024 + jj * 32;
        N0 = *(const float4*)(pb +  0); N1 = *(const float4*)(pb +  4);
        N2 = *(const float4*)(pb +  8); N3 = *(const float4*)(pb + 12);
        N4 = *(const float4*)(pb + 16); N5 = *(const float4*)(pb + 20);
        N6 = *(const float4*)(pb + 24); N7 = *(const float4*)(pb + 28);
      }
      als[jj] = a;   // duplicate write by lane and lane+32: same value
      float m = -1e30f;
      #define MAXQ(Q, b) \
        m = fmaxf(m, fmaxf(fmaxf(als[b+0] + Q.x, als[b+1] + Q.y), \
                           fmaxf(als[b+2] + Q.z, als[b+3] + Q.w)));
      MAXQ(P0, 0) MAXQ(P1, 4) MAXQ(P2, 8)  MAXQ(P3, 12)
      MAXQ(P4,16) MAXQ(P5,20) MAXQ(P6,24)  MAXQ(P7,28)
      float s = 0.f;
      #define SUMQ(Q, b) \
        s += __expf(als[b+0] + Q.x - m) + __expf(als[b+1] + Q.y - m) + \
             __expf(als[b+2] + Q.z - m) + __expf(als[b+3] + Q.w - m);
      SUMQ(P0, 0) SUMQ(P1, 4) SUMQ(P2, 8)  SUMQ(P3, 12)
      SUMQ(P4,16) SUMQ(P5,20) SUMQ(P6,24)  SUMQ(P7,28)
      #undef MAXQ
      #undef SUMQ
      a = m + __logf(s);
      P0 = N0; P1 = N1; P2 = N2; P3 = N3;
      P4 = N4; P5 = N5; P6 = N6; P7 = N7;
    }
    float x = (lane < 32) ? a + et[jj] : -1e30f;
    float mm = x;
    #pragma unroll
    for (int m2 = 1; m2 < 64; m2 <<= 1) mm = fmaxf(mm, __shfl_xor(mm, m2));
    float ss = (lane < 32) ? __expf(x - mm) : 0.f;
    #pragma unroll
    for (int m2 = 1; m2 < 64; m2 <<= 1) ss += __shfl_xor(ss, m2);
    if (lane == 0) gold[1] = mm + __logf(ss);
  }
  __syncthreads();
  if (tid == 0) out[0] = gold[1] - gold[0];
}

// ---------------------------------------------------------------------------
extern "C" void kernel_launch(void* const* d_in, const int* in_sizes, int n_in,
                              void* d_out, int out_size, void* d_ws, size_t ws_size,
                              hipStream_t stream) {
  const int*   ids   = (const int*)d_in[0];
  const int*   tgt   = (const int*)d_in[1];
  const float* emb   = (const float*)d_in[2];
  const float* wih_f = (const float*)d_in[3];
  const float* whh_f = (const float*)d_in[4];
  const float* b_f   = (const float*)d_in[5];
  const float* wih_b = (const float*)d_in[6];
  const float* whh_b = (const float*)d_in[7];
  const float* b_b   = (const float*)d_in[8];
  const float* lin_w = (const float*)d_in[9];
  const float* lin_b = (const float*)d_in[10];
  const float* st    = (const float*)d_in[11];
  const float* et    = (const float*)d_in[12];
  const float* trans = (const float*)d_in[13];

  float* xp_f = (float*)d_ws;                                   // 4096*2048
  float* xp_b = xp_f + (size_t)S_LEN * G4;                      // 4096*2048
  float* hs   = xp_b + (size_t)S_LEN * G4;                      // 4096*1024
  float* em   = hs   + (size_t)S_LEN * 1024;                    // 4096*32
  unsigned int* slot = (unsigned int*)(em + (size_t)S_LEN * 32);// 2*4*512
  float* Pt   = xp_f;   // reuse xp region (consumed before crf_pass1 runs)

  proj_gemm<<<dim3(16, 32, 2), dim3(256), 0, stream>>>(
      ids, emb, wih_f, wih_b, b_f, b_b, xp_f, xp_b);
  lstm_rec<<<dim3(32), dim3(512), 0, stream>>>(
      xp_f, xp_b, whh_f, whh_b, hs, slot);
  emis_kernel<<<dim3(256), dim3(512), 0, stream>>>(hs, lin_w, lin_b, em);
  crf_pass1<<<dim3(256), dim3(1024), 0, stream>>>(em, trans, Pt);
  crf_pass2<<<dim3(1), dim3(128), 0, stream>>>(em, Pt, tgt, st, et, trans,
                                               (float*)d_out);
}